// Round 9
// baseline (3836.427 us; speedup 1.0000x reference)
//
#include <hip/hip_runtime.h>

typedef short bf16x8 __attribute__((ext_vector_type(8)));
typedef unsigned short u16x8 __attribute__((ext_vector_type(8)));
typedef float f32x4 __attribute__((ext_vector_type(4)));

#define MFMA16(a, b, c) __builtin_amdgcn_mfma_f32_16x16x32_bf16((a), (b), (c), 0, 0, 0)

#define SCALEF 0.17677669529663687f  // 32^-0.5

__device__ __forceinline__ unsigned short f2bf(float f) {
  union { float f; unsigned u; } v; v.f = f;
  unsigned r = v.u + 0x7fffu + ((v.u >> 16) & 1u);  // RNE
  return (unsigned short)(r >> 16);
}
__device__ __forceinline__ float bf2f(unsigned short b) {
  union { unsigned u; float f; } v; v.u = ((unsigned)b) << 16;
  return v.f;
}

__device__ __forceinline__ void gl_lds16(const void* g, void* l) {
  __builtin_amdgcn_global_load_lds(
      (const __attribute__((address_space(1))) void*)g,
      (__attribute__((address_space(3))) void*)l, 16, 0, 0);
}

// ---------- prep kernels ----------
__global__ __launch_bounds__(256) void transpose_cvt_k(const float* __restrict__ W,
    unsigned short* __restrict__ Wt, int K, int N, float scale) {
  int i = blockIdx.x * 256 + threadIdx.x;
  if (i >= N * K) return;
  int n = i / K, k = i - n * K;
  Wt[i] = f2bf(W[(long)k * N + n] * scale);
}

__global__ __launch_bounds__(256) void scale_bias_k(const float* __restrict__ b,
    float* __restrict__ bs, float scale, int n) {
  int i = blockIdx.x * 256 + threadIdx.x;
  if (i < n) bs[i] = b[i] * scale;
}

// rpbp[h][q][lc*4+kt] = rpb[h][q][kt*16+lc]  (fragment-permuted, 256 KB f32)
__global__ __launch_bounds__(256) void build_rpbp_k(const float* __restrict__ bt,
    float* __restrict__ rpbp) {
  int i = blockIdx.x * 256 + threadIdx.x;
  if (i >= 16 * 64 * 64) return;
  int kt = i & 3, lcv = (i >> 2) & 15, q = (i >> 6) & 63, h = i >> 12;
  int k = kt * 16 + lcv;
  int dh = (q >> 3) - (k >> 3) + 7;
  int dw = (q & 7) - (k & 7) + 7;
  rpbp[i] = bt[(dh * 15 + dw) * 16 + h];
}

// fp32 -> bf16 bulk convert, 8 elems/thread
__global__ __launch_bounds__(256) void cvt_bf16_k(const float* __restrict__ in,
    unsigned short* __restrict__ out, int n8) {
  int i = blockIdx.x * 256 + threadIdx.x;
  if (i >= n8) return;
  const float4* p = (const float4*)(in + (size_t)i * 8);
  float4 a = p[0], b = p[1];
  uint4 pk;
  pk.x = (unsigned)f2bf(a.x) | ((unsigned)f2bf(a.y) << 16);
  pk.y = (unsigned)f2bf(a.z) | ((unsigned)f2bf(a.w) << 16);
  pk.z = (unsigned)f2bf(b.x) | ((unsigned)f2bf(b.y) << 16);
  pk.w = (unsigned)f2bf(b.z) | ((unsigned)f2bf(b.w) << 16);
  *(uint4*)(out + (size_t)i * 8) = pk;
}

// ---------- GEMM body (m97 structure, proven) ----------
template <typename OT>
__device__ __forceinline__ void gemm_body(const unsigned short* __restrict__ A,
    const unsigned short* __restrict__ Bt, const float* __restrict__ bias,
    OT* __restrict__ C, int M, int N, int K)
{
  constexpr bool O_F32 = (sizeof(OT) == 4);

  __shared__ __align__(16) char smem[32768];
  unsigned short* Asm = (unsigned short*)smem;
  unsigned short* Bsm = Asm + 8192;

  const int tn = N >> 7;
  const int nbm = M >> 7;
  const int g = blockIdx.x;
  const int xcd = g & 7;
  const int s = g >> 3;
  const int bm = xcd * (nbm >> 3) + (s / tn);
  const int bn = s - (s / tn) * tn;

  const int tid = threadIdx.x;
  const int wave = tid >> 6, lane = tid & 63;
  const int wr = wave >> 1, wc = wave & 1;
  const int lg = lane >> 4, lc = lane & 15;

  const long rowBase = (long)bm * 128;
  const int colBase = bn * 128;
  const int KT = K >> 6;

  f32x4 acc[4][4];
#pragma unroll
  for (int i = 0; i < 4; ++i)
#pragma unroll
    for (int j = 0; j < 4; ++j)
      acc[i][j] = f32x4{0.f, 0.f, 0.f, 0.f};

  const int blr = lane >> 3;
  const int bsw = (lane & 7) ^ blr;

  auto issueA = [&](int kt) {
#pragma unroll
    for (int j = 0; j < 4; ++j) {
      int r = j * 32 + wave * 8 + blr;
      gl_lds16(A + (rowBase + r) * (long)K + kt * 64 + bsw * 8,
               Asm + (j * 4 + wave) * 512);
    }
  };
  auto issueB = [&](int kt) {
#pragma unroll
    for (int j = 0; j < 4; ++j) {
      int r = j * 32 + wave * 8 + blr;
      gl_lds16(Bt + (long)(colBase + r) * K + kt * 64 + bsw * 8,
               Bsm + (j * 4 + wave) * 512);
    }
  };
  auto compute = [&]() {
#pragma unroll
    for (int ks = 0; ks < 2; ++ks) {
      const int ca = (ks * 4 + lg) ^ (lc & 7);
      bf16x8 af[4], bfr[4];
#pragma unroll
      for (int mt = 0; mt < 4; ++mt)
        af[mt] = *(const bf16x8*)(Asm + (wr * 64 + mt * 16 + lc) * 64 + ca * 8);
#pragma unroll
      for (int nt = 0; nt < 4; ++nt)
        bfr[nt] = *(const bf16x8*)(Bsm + (wc * 64 + nt * 16 + lc) * 64 + ca * 8);
#pragma unroll
      for (int mt = 0; mt < 4; ++mt)
#pragma unroll
        for (int nt = 0; nt < 4; ++nt)
          acc[mt][nt] = MFMA16(af[mt], bfr[nt], acc[mt][nt]);
    }
  };

  issueA(0); issueB(0);
  __syncthreads();

  for (int kt = 0; kt < KT; ++kt) {
    const bool more = (kt + 1 < KT);
    compute();
    __syncthreads();
    if (more) {
      issueA(kt + 1); issueB(kt + 1);
      __syncthreads();
    }
  }

  float bv[4];
#pragma unroll
  for (int nt = 0; nt < 4; ++nt)
    bv[nt] = bias[colBase + wc * 64 + nt * 16 + lc];

  if constexpr (O_F32) {
    float* Sf = (float*)smem;
#pragma unroll
    for (int h = 0; h < 2; ++h) {
      if (wr == h) {
#pragma unroll
        for (int mt = 0; mt < 4; ++mt)
#pragma unroll
          for (int nt = 0; nt < 4; ++nt)
#pragma unroll
            for (int r = 0; r < 4; ++r)
              Sf[(mt * 16 + lg * 4 + r) * 128 + wc * 64 + nt * 16 + lc] =
                  acc[mt][nt][r] + bv[nt];
      }
      __syncthreads();
#pragma unroll
      for (int p = 0; p < 8; ++p) {
        int ch = p * 256 + tid, row = ch >> 5, c = ch & 31;
        *(float4*)((float*)C + (rowBase + h * 64 + row) * N + colBase + c * 4) =
            *(const float4*)(Sf + row * 128 + c * 4);
      }
      __syncthreads();
    }
  } else {
    unsigned short* Su = (unsigned short*)smem;
#pragma unroll
    for (int h = 0; h < 2; ++h) {
      if (wr == h) {
#pragma unroll
        for (int mt = 0; mt < 4; ++mt)
#pragma unroll
          for (int nt = 0; nt < 4; ++nt)
#pragma unroll
            for (int r = 0; r < 4; ++r)
              Su[(mt * 16 + lg * 4 + r) * 128 + wc * 64 + nt * 16 + lc] =
                  f2bf(acc[mt][nt][r] + bv[nt]);
      }
      __syncthreads();
#pragma unroll
      for (int p = 0; p < 4; ++p) {
        int ch = p * 256 + tid, row = ch >> 4, c = ch & 15;
        *(uint4*)((unsigned short*)C + (rowBase + h * 64 + row) * N + colBase + c * 8) =
            *(const uint4*)(Su + row * 128 + c * 8);
      }
      __syncthreads();
    }
  }
}

__global__ __launch_bounds__(256, 5) void gemm_q_k(const unsigned short* __restrict__ A,
    const unsigned short* __restrict__ Bt, const float* __restrict__ bias,
    unsigned short* __restrict__ C, int M, int N, int K) {
  gemm_body<unsigned short>(A, Bt, bias, C, M, N, K);
}
__global__ __launch_bounds__(256, 5) void gemm_kv_k(const unsigned short* __restrict__ A,
    const unsigned short* __restrict__ Bt, const float* __restrict__ bias,
    unsigned short* __restrict__ C, int M, int N, int K) {
  gemm_body<unsigned short>(A, Bt, bias, C, M, N, K);
}
__global__ __launch_bounds__(256, 5) void gemm_out_k(const unsigned short* __restrict__ A,
    const unsigned short* __restrict__ Bt, const float* __restrict__ bias,
    float* __restrict__ C, int M, int N, int K) {
  gemm_body<float>(A, Bt, bias, C, M, N, K);
}

// ---------- fused window attention, head-cooperative + head-pipelined ----------
// grid = 4096 windows, 4 waves, ONE head at a time (16 sequential, 1 barrier
// each). Wave w owns q-rows w*16..w*16+15. V^T cooperative double-buffered
// staging. NEW: Q/K fragments for head h+1 issued right after head h's QK
// MFMAs (covered by softmax+PV+store+barrier). Loop unrolled x2 with named
// A/B register sets (rule #20: no runtime-indexed register arrays).
__global__ __launch_bounds__(256, 4) void attn_k(
    const unsigned short* __restrict__ qh,   // [B*64][512] bf16
    const unsigned short* __restrict__ kvh,  // [B*64][1024] bf16 (k | v)
    const float* __restrict__ mask,          // [64][64][64] f32
    const float* __restrict__ rpbp,          // [16][64][64] f32 permuted
    unsigned short* __restrict__ x)          // [B*64][512] bf16
{
  __shared__ unsigned short P[64][68];       // 8704 B (wave w: rows w*16..)
  __shared__ unsigned short Vt[2][32][68];   // 8704 B, double-buffered V^T
  __shared__ unsigned short maskS[64][68];   // 8704 B, permuted bf16 mask
  __shared__ unsigned short xs[4][16][40];   // 5120 B, out-staging

  const int b = blockIdx.x;
  const int w = b & 63;
  const int tid = threadIdx.x;
  const int wave = tid >> 6, lane = tid & 63;
  const int lg = lane >> 4, lc = lane & 15;
  const long rowQ = (long)b * 64;

  // stage mask once (permuted: col = (k&15)*4 + (k>>4))
#pragma unroll
  for (int t = 0; t < 16; ++t) {
    int i = t * 256 + tid;
    int qq = i >> 6, k = i & 63;
    maskS[qq][(k & 15) * 4 + (k >> 4)] = f2bf(mask[w * 4096 + i]);
  }

  // V staging geometry: thread -> (token = tid>>2, d-group = tid&3)
  const int vtok = tid >> 2, vg = tid & 3;
  const unsigned short* vbase = kvh + (rowQ + vtok) * 1024 + 512 + vg * 8;
  const unsigned short* qrow_p = qh + (rowQ + wave * 16 + lc) * 512 + lg * 8;

  // stage V[head 0] into buf 0
  {
    u16x8 v0 = *(const u16x8*)(vbase);
#pragma unroll
    for (int j = 0; j < 8; ++j) Vt[0][vg * 8 + j][vtok] = v0[j];
  }

  // prologue: head 0 Q/K fragments
  bf16x8 qfA, qfB, kfA[4], kfB[4];
  qfA = *(const bf16x8*)(qrow_p);
#pragma unroll
  for (int kt = 0; kt < 4; ++kt)
    kfA[kt] = *(const bf16x8*)(kvh + (rowQ + kt * 16 + lc) * 1024 + lg * 8);

  __syncthreads();

  auto body = [&](int h, bf16x8& qfc, bf16x8 (&kfc)[4],
                  bf16x8& qfn, bf16x8 (&kfn)[4], bool pre) {
    const int cur = h & 1;

    // prefetch next head's V slice into regs (hidden under QK+softmax)
    u16x8 vn;
    if (h < 15) vn = *(const u16x8*)(vbase + (h + 1) * 32);

    f32x4 acc[4];
#pragma unroll
    for (int kt = 0; kt < 4; ++kt) acc[kt] = f32x4{0.f, 0.f, 0.f, 0.f};
#pragma unroll
    for (int kt = 0; kt < 4; ++kt) acc[kt] = MFMA16(qfc, kfc[kt], acc[kt]);

    // issue next head's Q/K fragments (consumed next iteration)
    if (pre) {
      qfn = *(const bf16x8*)(qrow_p + (h + 1) * 32);
#pragma unroll
      for (int kt = 0; kt < 4; ++kt)
        kfn[kt] = *(const bf16x8*)(kvh + (rowQ + kt * 16 + lc) * 1024 +
                                   (h + 1) * 32 + lg * 8);
    }

    // softmax: lane handles rows q = wave*16 + lg*4 + r
    float pden[4];
#pragma unroll
    for (int r = 0; r < 4; ++r) {
      const int qrow = wave * 16 + lg * 4 + r;
      f32x4 rp = *(const f32x4*)(rpbp + (h << 12) + qrow * 64 + lc * 4);
      ushort4 mv = *(const ushort4*)&maskS[qrow][lc * 4];
      float sc[4];
      sc[0] = acc[0][r] + rp[0] + bf2f(mv.x);
      sc[1] = acc[1][r] + rp[1] + bf2f(mv.y);
      sc[2] = acc[2][r] + rp[2] + bf2f(mv.z);
      sc[3] = acc[3][r] + rp[3] + bf2f(mv.w);
      float mx = fmaxf(fmaxf(sc[0], sc[1]), fmaxf(sc[2], sc[3]));
      mx = fmaxf(mx, __shfl_xor(mx, 1));
      mx = fmaxf(mx, __shfl_xor(mx, 2));
      mx = fmaxf(mx, __shfl_xor(mx, 4));
      mx = fmaxf(mx, __shfl_xor(mx, 8));
      float s = 0.f;
#pragma unroll
      for (int kt = 0; kt < 4; ++kt) { sc[kt] = __expf(sc[kt] - mx); s += sc[kt]; }
      s += __shfl_xor(s, 1);
      s += __shfl_xor(s, 2);
      s += __shfl_xor(s, 4);
      s += __shfl_xor(s, 8);
      pden[r] = 1.f / s;
#pragma unroll
      for (int kt = 0; kt < 4; ++kt)
        P[qrow][kt * 16 + lc] = f2bf(sc[kt]);
    }

    // write next head's V^T into the other buffer (readers finished last iter)
    if (h < 15) {
#pragma unroll
      for (int j = 0; j < 8; ++j) Vt[cur ^ 1][vg * 8 + j][vtok] = vn[j];
    }

    // PV: wave-private P rows, no barrier needed before this
    f32x4 xacc[2];
    xacc[0] = f32x4{0.f, 0.f, 0.f, 0.f};
    xacc[1] = f32x4{0.f, 0.f, 0.f, 0.f};
#pragma unroll
    for (int ks = 0; ks < 2; ++ks) {
      bf16x8 pa = *(const bf16x8*)&P[wave * 16 + lc][ks * 32 + lg * 8];
      bf16x8 vb0 = *(const bf16x8*)&Vt[cur][lc][ks * 32 + lg * 8];
      bf16x8 vb1 = *(const bf16x8*)&Vt[cur][16 + lc][ks * 32 + lg * 8];
      xacc[0] = MFMA16(pa, vb0, xacc[0]);
      xacc[1] = MFMA16(pa, vb1, xacc[1]);
    }

    // normalize -> xs -> full-sector 64B stores
#pragma unroll
    for (int dt = 0; dt < 2; ++dt)
#pragma unroll
      for (int r = 0; r < 4; ++r)
        xs[wave][lg * 4 + r][dt * 16 + lc] = f2bf(xacc[dt][r] * pden[r]);
    {
      int row = lane >> 2, c = lane & 3;
      uint4 v = *(const uint4*)&xs[wave][row][c * 8];
      *(uint4*)(x + (rowQ + wave * 16 + row) * 512 + h * 32 + c * 8) = v;
    }

    __syncthreads();  // Vt[cur] readers done before next iter overwrites
  };

  for (int hh = 0; hh < 8; ++hh) {
    body(2 * hh,     qfA, kfA, qfB, kfB, true);
    body(2 * hh + 1, qfB, kfB, qfA, kfA, (2 * hh + 1) < 15);
  }
}

extern "C" void kernel_launch(void* const* d_in, const int* in_sizes, int n_in,
                              void* d_out, int out_size, void* d_ws, size_t ws_size,
                              hipStream_t stream) {
  const float* q    = (const float*)d_in[0];
  const float* kv   = (const float*)d_in[1];
  const float* mask = (const float*)d_in[2];
  const float* Wq   = (const float*)d_in[3];
  const float* bq   = (const float*)d_in[4];
  const float* Wkv  = (const float*)d_in[5];
  const float* bkv  = (const float*)d_in[6];
  const float* btab = (const float*)d_in[7];
  const float* Wp   = (const float*)d_in[8];
  const float* bp   = (const float*)d_in[9];
  float* out = (float*)d_out;

  const int M = 4096 * 64;  // 262144 rows

  char* ws = (char*)d_ws;
  const size_t OFF_QH   = 0;                               // 256 MB
  const size_t OFF_KVH  = OFF_QH + (size_t)M * 512 * 2;    // 512 MB
  const size_t OFF_SCR  = OFF_KVH + (size_t)M * 1024 * 2;  // 256 MB time-shared
  const size_t OFF_WQT  = OFF_SCR + (size_t)M * 512 * 2;
  const size_t OFF_WKVT = OFF_WQT + 512 * 512 * 2;
  const size_t OFF_WPT  = OFF_WKVT + 1024 * 512 * 2;
  const size_t OFF_RPBP = OFF_WPT + 512 * 512 * 2;         // 256 KB
  const size_t OFF_BQS  = OFF_RPBP + 16 * 64 * 64 * 4;     // 2 KB

  unsigned short* qh    = (unsigned short*)(ws + OFF_QH);
  unsigned short* kvh   = (unsigned short*)(ws + OFF_KVH);
  unsigned short* scr   = (unsigned short*)(ws + OFF_SCR); // kvbf -> qbf -> xb
  unsigned short* Wq_t  = (unsigned short*)(ws + OFF_WQT);
  unsigned short* Wkv_t = (unsigned short*)(ws + OFF_WKVT);
  unsigned short* Wp_t  = (unsigned short*)(ws + OFF_WPT);
  float* rpbp           = (float*)(ws + OFF_RPBP);
  float* bq_s           = (float*)(ws + OFF_BQS);

  transpose_cvt_k<<<(512 * 512 + 255) / 256, 256, 0, stream>>>(Wq, Wq_t, 512, 512, SCALEF);
  transpose_cvt_k<<<(512 * 1024 + 255) / 256, 256, 0, stream>>>(Wkv, Wkv_t, 512, 1024, 1.0f);
  transpose_cvt_k<<<(512 * 512 + 255) / 256, 256, 0, stream>>>(Wp, Wp_t, 512, 512, 1.0f);
  scale_bias_k<<<2, 256, 0, stream>>>(bq, bq_s, SCALEF, 512);
  build_rpbp_k<<<(16 * 64 * 64) / 256, 256, 0, stream>>>(btab, rpbp);

  const int n8 = M * 512 / 8;

  cvt_bf16_k<<<n8 / 256, 256, 0, stream>>>(kv, scr, n8);
  gemm_kv_k<<<(M / 128) * (1024 / 128), 256, 0, stream>>>(scr, Wkv_t, bkv, kvh, M, 1024, 512);

  cvt_bf16_k<<<n8 / 256, 256, 0, stream>>>(q, scr, n8);
  gemm_q_k<<<(M / 128) * (512 / 128), 256, 0, stream>>>(scr, Wq_t, bq_s, qh, M, 512, 512);

  attn_k<<<4096, 256, 0, stream>>>(qh, kvh, mask, rpbp, scr);

  gemm_out_k<<<(M / 128) * (512 / 128), 256, 0, stream>>>(scr, Wp_t, bp, out, M, 512, 512);

  (void)in_sizes; (void)n_in; (void)out_size; (void)ws_size;
}

// Round 10
// 1310.882 us; speedup vs baseline: 2.9266x; 2.9266x over previous
//
#include <hip/hip_runtime.h>
#include <hip/hip_bf16.h>

typedef short bf16x8 __attribute__((ext_vector_type(8)));
typedef unsigned short u16x8 __attribute__((ext_vector_type(8)));
typedef float f32x4 __attribute__((ext_vector_type(4)));

#define MFMA16(a, b, c) __builtin_amdgcn_mfma_f32_16x16x32_bf16((a), (b), (c), 0, 0, 0)

#define SCALEF 0.17677669529663687f  // 32^-0.5

__device__ __forceinline__ unsigned short f2bf(float f) {
  union { float f; unsigned u; } v; v.f = f;
  unsigned r = v.u + 0x7fffu + ((v.u >> 16) & 1u);  // RNE
  return (unsigned short)(r >> 16);
}
__device__ __forceinline__ float bf2f(unsigned short b) {
  union { unsigned u; float f; } v; v.u = ((unsigned)b) << 16;
  return v.f;
}

__device__ __forceinline__ void gl_lds16(const void* g, void* l) {
  __builtin_amdgcn_global_load_lds(
      (const __attribute__((address_space(1))) void*)g,
      (__attribute__((address_space(3))) void*)l, 16, 0, 0);
}

// 8 f32 -> bf16x8 via compiler bf16 casts (hw cvt on gfx950, RNE)
__device__ __forceinline__ bf16x8 cvt8(f32x4 a, f32x4 b) {
  bf16x8 r;
#pragma unroll
  for (int i = 0; i < 4; ++i) {
    union { __hip_bfloat16 h; short s; } u;
    u.h = __hip_bfloat16(a[i]);
    r[i] = u.s;
  }
#pragma unroll
  for (int i = 0; i < 4; ++i) {
    union { __hip_bfloat16 h; short s; } u;
    u.h = __hip_bfloat16(b[i]);
    r[4 + i] = u.s;
  }
  return r;
}

// ---------- prep kernels ----------
__global__ __launch_bounds__(256) void transpose_cvt_k(const float* __restrict__ W,
    unsigned short* __restrict__ Wt, int K, int N, float scale) {
  int i = blockIdx.x * 256 + threadIdx.x;
  if (i >= N * K) return;
  int n = i / K, k = i - n * K;
  Wt[i] = f2bf(W[(long)k * N + n] * scale);
}

__global__ __launch_bounds__(256) void scale_bias_k(const float* __restrict__ b,
    float* __restrict__ bs, float scale, int n) {
  int i = blockIdx.x * 256 + threadIdx.x;
  if (i < n) bs[i] = b[i] * scale;
}

// rpbp[h][q][lc*4+kt] = rpb[h][q][kt*16+lc]  (fragment-permuted, 256 KB f32)
__global__ __launch_bounds__(256) void build_rpbp_k(const float* __restrict__ bt,
    float* __restrict__ rpbp) {
  int i = blockIdx.x * 256 + threadIdx.x;
  if (i >= 16 * 64 * 64) return;
  int kt = i & 3, lcv = (i >> 2) & 15, q = (i >> 6) & 63, h = i >> 12;
  int k = kt * 16 + lcv;
  int dh = (q >> 3) - (k >> 3) + 7;
  int dw = (q & 7) - (k & 7) + 7;
  rpbp[i] = bt[(dh * 15 + dw) * 16 + h];
}

// fp32 -> bf16 bulk convert, 8 elems/thread
__global__ __launch_bounds__(256) void cvt_bf16_k(const float* __restrict__ in,
    unsigned short* __restrict__ out, int n8) {
  int i = blockIdx.x * 256 + threadIdx.x;
  if (i >= n8) return;
  const float4* p = (const float4*)(in + (size_t)i * 8);
  float4 a = p[0], b = p[1];
  uint4 pk;
  pk.x = (unsigned)f2bf(a.x) | ((unsigned)f2bf(a.y) << 16);
  pk.y = (unsigned)f2bf(a.z) | ((unsigned)f2bf(a.w) << 16);
  pk.z = (unsigned)f2bf(b.x) | ((unsigned)f2bf(b.y) << 16);
  pk.w = (unsigned)f2bf(b.z) | ((unsigned)f2bf(b.w) << 16);
  *(uint4*)(out + (size_t)i * 8) = pk;
}

// ---------- GEMM body (m97 structure, proven; bf16 A) ----------
template <typename OT>
__device__ __forceinline__ void gemm_body(const unsigned short* __restrict__ A,
    const unsigned short* __restrict__ Bt, const float* __restrict__ bias,
    OT* __restrict__ C, int M, int N, int K)
{
  constexpr bool O_F32 = (sizeof(OT) == 4);

  __shared__ __align__(16) char smem[32768];
  unsigned short* Asm = (unsigned short*)smem;
  unsigned short* Bsm = Asm + 8192;

  const int tn = N >> 7;
  const int nbm = M >> 7;
  const int g = blockIdx.x;
  const int xcd = g & 7;
  const int s = g >> 3;
  const int bm = xcd * (nbm >> 3) + (s / tn);
  const int bn = s - (s / tn) * tn;

  const int tid = threadIdx.x;
  const int wave = tid >> 6, lane = tid & 63;
  const int wr = wave >> 1, wc = wave & 1;
  const int lg = lane >> 4, lc = lane & 15;

  const long rowBase = (long)bm * 128;
  const int colBase = bn * 128;
  const int KT = K >> 6;

  f32x4 acc[4][4];
#pragma unroll
  for (int i = 0; i < 4; ++i)
#pragma unroll
    for (int j = 0; j < 4; ++j)
      acc[i][j] = f32x4{0.f, 0.f, 0.f, 0.f};

  const int blr = lane >> 3;
  const int bsw = (lane & 7) ^ blr;

  auto issueA = [&](int kt) {
#pragma unroll
    for (int j = 0; j < 4; ++j) {
      int r = j * 32 + wave * 8 + blr;
      gl_lds16(A + (rowBase + r) * (long)K + kt * 64 + bsw * 8,
               Asm + (j * 4 + wave) * 512);
    }
  };
  auto issueB = [&](int kt) {
#pragma unroll
    for (int j = 0; j < 4; ++j) {
      int r = j * 32 + wave * 8 + blr;
      gl_lds16(Bt + (long)(colBase + r) * K + kt * 64 + bsw * 8,
               Bsm + (j * 4 + wave) * 512);
    }
  };
  auto compute = [&]() {
#pragma unroll
    for (int ks = 0; ks < 2; ++ks) {
      const int ca = (ks * 4 + lg) ^ (lc & 7);
      bf16x8 af[4], bfr[4];
#pragma unroll
      for (int mt = 0; mt < 4; ++mt)
        af[mt] = *(const bf16x8*)(Asm + (wr * 64 + mt * 16 + lc) * 64 + ca * 8);
#pragma unroll
      for (int nt = 0; nt < 4; ++nt)
        bfr[nt] = *(const bf16x8*)(Bsm + (wc * 64 + nt * 16 + lc) * 64 + ca * 8);
#pragma unroll
      for (int mt = 0; mt < 4; ++mt)
#pragma unroll
        for (int nt = 0; nt < 4; ++nt)
          acc[mt][nt] = MFMA16(af[mt], bfr[nt], acc[mt][nt]);
    }
  };

  issueA(0); issueB(0);
  __syncthreads();

  for (int kt = 0; kt < KT; ++kt) {
    const bool more = (kt + 1 < KT);
    compute();
    __syncthreads();
    if (more) {
      issueA(kt + 1); issueB(kt + 1);
      __syncthreads();
    }
  }

  float bv[4];
#pragma unroll
  for (int nt = 0; nt < 4; ++nt)
    bv[nt] = bias[colBase + wc * 64 + nt * 16 + lc];

  if constexpr (O_F32) {
    float* Sf = (float*)smem;
#pragma unroll
    for (int h = 0; h < 2; ++h) {
      if (wr == h) {
#pragma unroll
        for (int mt = 0; mt < 4; ++mt)
#pragma unroll
          for (int nt = 0; nt < 4; ++nt)
#pragma unroll
            for (int r = 0; r < 4; ++r)
              Sf[(mt * 16 + lg * 4 + r) * 128 + wc * 64 + nt * 16 + lc] =
                  acc[mt][nt][r] + bv[nt];
      }
      __syncthreads();
#pragma unroll
      for (int p = 0; p < 8; ++p) {
        int ch = p * 256 + tid, row = ch >> 5, c = ch & 31;
        *(float4*)((float*)C + (rowBase + h * 64 + row) * N + colBase + c * 4) =
            *(const float4*)(Sf + row * 128 + c * 4);
      }
      __syncthreads();
    }
  } else {
    unsigned short* Su = (unsigned short*)smem;
#pragma unroll
    for (int h = 0; h < 2; ++h) {
      if (wr == h) {
#pragma unroll
        for (int mt = 0; mt < 4; ++mt)
#pragma unroll
          for (int nt = 0; nt < 4; ++nt)
#pragma unroll
            for (int r = 0; r < 4; ++r)
              Su[(mt * 16 + lg * 4 + r) * 128 + wc * 64 + nt * 16 + lc] =
                  f2bf(acc[mt][nt][r] + bv[nt]);
      }
      __syncthreads();
#pragma unroll
      for (int p = 0; p < 4; ++p) {
        int ch = p * 256 + tid, row = ch >> 4, c = ch & 15;
        *(uint4*)((unsigned short*)C + (rowBase + h * 64 + row) * N + colBase + c * 8) =
            *(const uint4*)(Su + row * 128 + c * 8);
      }
      __syncthreads();
    }
  }
}

__global__ __launch_bounds__(256, 4) void gemm_kv_k(const unsigned short* __restrict__ A,
    const unsigned short* __restrict__ Bt, const float* __restrict__ bias,
    unsigned short* __restrict__ C, int M, int N, int K) {
  gemm_body<unsigned short>(A, Bt, bias, C, M, N, K);
}
__global__ __launch_bounds__(256, 4) void gemm_out_k(const unsigned short* __restrict__ A,
    const unsigned short* __restrict__ Bt, const float* __restrict__ bias,
    float* __restrict__ C, int M, int N, int K) {
  gemm_body<float>(A, Bt, bias, C, M, N, K);
}

// ---------- Q-proj GEMM with fused fp32->bf16 A (gl_lds f32 tile) ----------
// m97 skeleton; A streams fp32 via global_load_lds into a 32 KB XOR-swizzled
// f32 tile ([128 rows][16 chunks of 16B], chunk ^= row&15, both sides);
// conversion to bf16 happens at ds_read time (hw cvt). LDS 48 KB, 3 blocks/CU.
__global__ __launch_bounds__(256, 3) void gemm_qf_k(const float* __restrict__ A,
    const unsigned short* __restrict__ Bt, const float* __restrict__ bias,
    unsigned short* __restrict__ C, int M, int N, int K)
{
  __shared__ __align__(16) char smem[49152];
  float* Af = (float*)smem;                               // [128][64] f32, 32 KB
  unsigned short* Bsm = (unsigned short*)(smem + 32768);  // [128][64] bf16, 16 KB

  const int tn = N >> 7;
  const int nbm = M >> 7;
  const int g = blockIdx.x;
  const int xcd = g & 7;
  const int s = g >> 3;
  const int bm = xcd * (nbm >> 3) + (s / tn);
  const int bn = s - (s / tn) * tn;

  const int tid = threadIdx.x;
  const int wave = tid >> 6, lane = tid & 63;
  const int wr = wave >> 1, wc = wave & 1;
  const int lg = lane >> 4, lc = lane & 15;

  const long rowBase = (long)bm * 128;
  const int colBase = bn * 128;
  const int KT = K >> 6;

  f32x4 acc[4][4];
#pragma unroll
  for (int i = 0; i < 4; ++i)
#pragma unroll
    for (int j = 0; j < 4; ++j)
      acc[i][j] = f32x4{0.f, 0.f, 0.f, 0.f};

  // B staging (8 chunks/row, chunk ^= row&7)
  const int blr = lane >> 3;
  const int bsw = (lane & 7) ^ blr;
  // A staging (f32, 16 chunks/row, chunk ^= row&15): issue = 4 rows x 16 chunks
  const int alr = lane >> 4;          // row-in-4
  const int achk = lane & 15;

  auto issueA = [&](int kt) {
#pragma unroll
    for (int j = 0; j < 8; ++j) {
      int r = (j * 4 + wave) * 4 + alr;
      int swc = achk ^ (r & 15);
      gl_lds16(A + (rowBase + r) * (long)K + kt * 64 + swc * 4,
               Af + (j * 4 + wave) * 256);
    }
  };
  auto issueB = [&](int kt) {
#pragma unroll
    for (int j = 0; j < 4; ++j) {
      int r = j * 32 + wave * 8 + blr;
      gl_lds16(Bt + (long)(colBase + r) * K + kt * 64 + bsw * 8,
               Bsm + (j * 4 + wave) * 512);
    }
  };
  auto compute = [&]() {
#pragma unroll
    for (int ks = 0; ks < 2; ++ks) {
      const int cb = (ks * 4 + lg) ^ (lc & 7);
      bf16x8 af[4], bfr[4];
#pragma unroll
      for (int mt = 0; mt < 4; ++mt) {
        const int row = wr * 64 + mt * 16 + lc;     // row & 15 == lc
        const int c0 = ks * 8 + lg * 2;
        f32x4 f0 = *(const f32x4*)(Af + row * 64 + ((c0)     ^ lc) * 4);
        f32x4 f1 = *(const f32x4*)(Af + row * 64 + ((c0 + 1) ^ lc) * 4);
        af[mt] = cvt8(f0, f1);
      }
#pragma unroll
      for (int nt = 0; nt < 4; ++nt)
        bfr[nt] = *(const bf16x8*)(Bsm + (wc * 64 + nt * 16 + lc) * 64 + cb * 8);
#pragma unroll
      for (int mt = 0; mt < 4; ++mt)
#pragma unroll
        for (int nt = 0; nt < 4; ++nt)
          acc[mt][nt] = MFMA16(af[mt], bfr[nt], acc[mt][nt]);
    }
  };

  issueA(0); issueB(0);
  __syncthreads();

  for (int kt = 0; kt < KT; ++kt) {
    const bool more = (kt + 1 < KT);
    compute();
    __syncthreads();
    if (more) {
      issueA(kt + 1); issueB(kt + 1);
      __syncthreads();
    }
  }

  float bv[4];
#pragma unroll
  for (int nt = 0; nt < 4; ++nt)
    bv[nt] = bias[colBase + wc * 64 + nt * 16 + lc];

  // bf16 epilogue (staged, full-sector stores)
  unsigned short* Su = (unsigned short*)smem;
#pragma unroll
  for (int h = 0; h < 2; ++h) {
    __syncthreads();
    if (wr == h) {
#pragma unroll
      for (int mt = 0; mt < 4; ++mt)
#pragma unroll
        for (int nt = 0; nt < 4; ++nt)
#pragma unroll
          for (int r = 0; r < 4; ++r)
            Su[(mt * 16 + lg * 4 + r) * 128 + wc * 64 + nt * 16 + lc] =
                f2bf(acc[mt][nt][r] + bv[nt]);
    }
    __syncthreads();
#pragma unroll
    for (int p = 0; p < 4; ++p) {
      int ch = p * 256 + tid, row = ch >> 4, c = ch & 15;
      *(uint4*)(C + (rowBase + h * 64 + row) * N + colBase + c * 8) =
          *(const uint4*)(Su + row * 128 + c * 8);
    }
  }
}

// ---------- fused window attention, head-cooperative (R8, measured) ----------
__global__ __launch_bounds__(256, 5) void attn_k(
    const unsigned short* __restrict__ qh,   // [B*64][512] bf16
    const unsigned short* __restrict__ kvh,  // [B*64][1024] bf16 (k | v)
    const float* __restrict__ mask,          // [64][64][64] f32
    const float* __restrict__ rpbp,          // [16][64][64] f32 permuted
    unsigned short* __restrict__ x)          // [B*64][512] bf16
{
  __shared__ unsigned short P[64][68];       // 8704 B (wave w: rows w*16..)
  __shared__ unsigned short Vt[2][32][68];   // 8704 B, double-buffered V^T
  __shared__ unsigned short maskS[64][68];   // 8704 B, permuted bf16 mask
  __shared__ unsigned short xs[4][16][40];   // 5120 B, out-staging

  const int b = blockIdx.x;
  const int w = b & 63;
  const int tid = threadIdx.x;
  const int wave = tid >> 6, lane = tid & 63;
  const int lg = lane >> 4, lc = lane & 15;
  const long rowQ = (long)b * 64;

  // stage mask once (permuted: col = (k&15)*4 + (k>>4))
#pragma unroll
  for (int t = 0; t < 16; ++t) {
    int i = t * 256 + tid;
    int qq = i >> 6, k = i & 63;
    maskS[qq][(k & 15) * 4 + (k >> 4)] = f2bf(mask[w * 4096 + i]);
  }

  // V staging geometry: thread -> (token = tid>>2, d-group = tid&3)
  const int vtok = tid >> 2, vg = tid & 3;
  const unsigned short* vbase = kvh + (rowQ + vtok) * 1024 + 512 + vg * 8;

  // stage V[head 0] into buf 0
  {
    u16x8 v0 = *(const u16x8*)(vbase);
#pragma unroll
    for (int j = 0; j < 8; ++j) Vt[0][vg * 8 + j][vtok] = v0[j];
  }
  __syncthreads();

  for (int h = 0; h < 16; ++h) {
    const int cur = h & 1;

    // prefetch next head's V slice into regs (hidden under QK+softmax)
    u16x8 vn;
    if (h < 15) vn = *(const u16x8*)(vbase + (h + 1) * 32);

    // Q frag (wave's 16 rows) + K frags (all 64 tokens, L1-shared)
    bf16x8 qf = *(const bf16x8*)(qh + (rowQ + wave * 16 + lc) * 512 + h * 32 + lg * 8);
    bf16x8 kf[4];
#pragma unroll
    for (int kt = 0; kt < 4; ++kt)
      kf[kt] = *(const bf16x8*)(kvh + (rowQ + kt * 16 + lc) * 1024 + h * 32 + lg * 8);

    f32x4 acc[4];
#pragma unroll
    for (int kt = 0; kt < 4; ++kt) acc[kt] = f32x4{0.f, 0.f, 0.f, 0.f};
#pragma unroll
    for (int kt = 0; kt < 4; ++kt) acc[kt] = MFMA16(qf, kf[kt], acc[kt]);

    // softmax: lane handles rows q = wave*16 + lg*4 + r
    float pden[4];
#pragma unroll
    for (int r = 0; r < 4; ++r) {
      const int qrow = wave * 16 + lg * 4 + r;
      f32x4 rp = *(const f32x4*)(rpbp + (h << 12) + qrow * 64 + lc * 4);
      ushort4 mv = *(const ushort4*)&maskS[qrow][lc * 4];
      float sc[4];
      sc[0] = acc[0][r] + rp[0] + bf2f(mv.x);
      sc[1] = acc[1][r] + rp[1] + bf2f(mv.y);
      sc[2] = acc[2][r] + rp[2] + bf2f(mv.z);
      sc[3] = acc[3][r] + rp[3] + bf2f(mv.w);
      float mx = fmaxf(fmaxf(sc[0], sc[1]), fmaxf(sc[2], sc[3]));
      mx = fmaxf(mx, __shfl_xor(mx, 1));
      mx = fmaxf(mx, __shfl_xor(mx, 2));
      mx = fmaxf(mx, __shfl_xor(mx, 4));
      mx = fmaxf(mx, __shfl_xor(mx, 8));
      float s = 0.f;
#pragma unroll
      for (int kt = 0; kt < 4; ++kt) { sc[kt] = __expf(sc[kt] - mx); s += sc[kt]; }
      s += __shfl_xor(s, 1);
      s += __shfl_xor(s, 2);
      s += __shfl_xor(s, 4);
      s += __shfl_xor(s, 8);
      pden[r] = 1.f / s;
#pragma unroll
      for (int kt = 0; kt < 4; ++kt)
        P[qrow][kt * 16 + lc] = f2bf(sc[kt]);
    }

    // write next head's V^T into the other buffer (readers finished last iter)
    if (h < 15) {
#pragma unroll
      for (int j = 0; j < 8; ++j) Vt[cur ^ 1][vg * 8 + j][vtok] = vn[j];
    }

    // PV: out[q][d] for wave's rows; P rows are wave-private (no barrier)
    f32x4 xacc[2];
    xacc[0] = f32x4{0.f, 0.f, 0.f, 0.f};
    xacc[1] = f32x4{0.f, 0.f, 0.f, 0.f};
#pragma unroll
    for (int ks = 0; ks < 2; ++ks) {
      bf16x8 pa = *(const bf16x8*)&P[wave * 16 + lc][ks * 32 + lg * 8];
      bf16x8 vb0 = *(const bf16x8*)&Vt[cur][lc][ks * 32 + lg * 8];
      bf16x8 vb1 = *(const bf16x8*)&Vt[cur][16 + lc][ks * 32 + lg * 8];
      xacc[0] = MFMA16(pa, vb0, xacc[0]);
      xacc[1] = MFMA16(pa, vb1, xacc[1]);
    }

    // normalize -> xs -> full-sector 64B stores
#pragma unroll
    for (int dt = 0; dt < 2; ++dt)
#pragma unroll
      for (int r = 0; r < 4; ++r)
        xs[wave][lg * 4 + r][dt * 16 + lc] = f2bf(xacc[dt][r] * pden[r]);
    {
      int row = lane >> 2, c = lane & 3;
      uint4 v = *(const uint4*)&xs[wave][row][c * 8];
      *(uint4*)(x + (rowQ + wave * 16 + row) * 512 + h * 32 + c * 8) = v;
    }

    __syncthreads();  // Vt[cur] readers done before iter h+1 writes it
  }
}

extern "C" void kernel_launch(void* const* d_in, const int* in_sizes, int n_in,
                              void* d_out, int out_size, void* d_ws, size_t ws_size,
                              hipStream_t stream) {
  const float* q    = (const float*)d_in[0];
  const float* kv   = (const float*)d_in[1];
  const float* mask = (const float*)d_in[2];
  const float* Wq   = (const float*)d_in[3];
  const float* bq   = (const float*)d_in[4];
  const float* Wkv  = (const float*)d_in[5];
  const float* bkv  = (const float*)d_in[6];
  const float* btab = (const float*)d_in[7];
  const float* Wp   = (const float*)d_in[8];
  const float* bp   = (const float*)d_in[9];
  float* out = (float*)d_out;

  const int M = 4096 * 64;  // 262144 rows

  char* ws = (char*)d_ws;
  const size_t OFF_QH   = 0;                               // 256 MB
  const size_t OFF_KVH  = OFF_QH + (size_t)M * 512 * 2;    // 512 MB
  const size_t OFF_SCR  = OFF_KVH + (size_t)M * 1024 * 2;  // 256 MB (kvbf -> xb)
  const size_t OFF_WQT  = OFF_SCR + (size_t)M * 512 * 2;
  const size_t OFF_WKVT = OFF_WQT + 512 * 512 * 2;
  const size_t OFF_WPT  = OFF_WKVT + 1024 * 512 * 2;
  const size_t OFF_RPBP = OFF_WPT + 512 * 512 * 2;         // 256 KB
  const size_t OFF_BQS  = OFF_RPBP + 16 * 64 * 64 * 4;     // 2 KB

  unsigned short* qh    = (unsigned short*)(ws + OFF_QH);
  unsigned short* kvh   = (unsigned short*)(ws + OFF_KVH);
  unsigned short* scr   = (unsigned short*)(ws + OFF_SCR); // kvbf -> xb
  unsigned short* Wq_t  = (unsigned short*)(ws + OFF_WQT);
  unsigned short* Wkv_t = (unsigned short*)(ws + OFF_WKVT);
  unsigned short* Wp_t  = (unsigned short*)(ws + OFF_WPT);
  float* rpbp           = (float*)(ws + OFF_RPBP);
  float* bq_s           = (float*)(ws + OFF_BQS);

  transpose_cvt_k<<<(512 * 512 + 255) / 256, 256, 0, stream>>>(Wq, Wq_t, 512, 512, SCALEF);
  transpose_cvt_k<<<(512 * 1024 + 255) / 256, 256, 0, stream>>>(Wkv, Wkv_t, 512, 1024, 1.0f);
  transpose_cvt_k<<<(512 * 512 + 255) / 256, 256, 0, stream>>>(Wp, Wp_t, 512, 512, 1.0f);
  scale_bias_k<<<2, 256, 0, stream>>>(bq, bq_s, SCALEF, 512);
  build_rpbp_k<<<(16 * 64 * 64) / 256, 256, 0, stream>>>(btab, rpbp);

  const int n8 = M * 512 / 8;

  // kv -> bf16 -> KV-proj (scratch holds kvbf)
  cvt_bf16_k<<<n8 / 256, 256, 0, stream>>>(kv, scr, n8);
  gemm_kv_k<<<(M / 128) * (1024 / 128), 256, 0, stream>>>(scr, Wkv_t, bkv, kvh, M, 1024, 512);

  // Q-proj reads fp32 q directly (fused conversion)
  gemm_qf_k<<<(M / 128) * (512 / 128), 256, 0, stream>>>(q, Wq_t, bq_s, qh, M, 512, 512);

  // attention (scratch reused for xb)
  attn_k<<<4096, 256, 0, stream>>>(qh, kvh, mask, rpbp, scr);

  gemm_out_k<<<(M / 128) * (512 / 128), 256, 0, stream>>>(scr, Wp_t, bp, out, M, 512, 512);

  (void)in_sizes; (void)n_in; (void)out_size; (void)ws_size;
}

// Round 11
// 1298.391 us; speedup vs baseline: 2.9548x; 1.0096x over previous
//
#include <hip/hip_runtime.h>
#include <hip/hip_bf16.h>

typedef short bf16x8 __attribute__((ext_vector_type(8)));
typedef unsigned short u16x8 __attribute__((ext_vector_type(8)));
typedef float f32x4 __attribute__((ext_vector_type(4)));

#define MFMA16(a, b, c) __builtin_amdgcn_mfma_f32_16x16x32_bf16((a), (b), (c), 0, 0, 0)

#define SCALEF 0.17677669529663687f  // 32^-0.5

__device__ __forceinline__ unsigned short f2bf(float f) {
  union { float f; unsigned u; } v; v.f = f;
  unsigned r = v.u + 0x7fffu + ((v.u >> 16) & 1u);  // RNE
  return (unsigned short)(r >> 16);
}
__device__ __forceinline__ float bf2f(unsigned short b) {
  union { unsigned u; float f; } v; v.u = ((unsigned)b) << 16;
  return v.f;
}

__device__ __forceinline__ void gl_lds16(const void* g, void* l) {
  __builtin_amdgcn_global_load_lds(
      (const __attribute__((address_space(1))) void*)g,
      (__attribute__((address_space(3))) void*)l, 16, 0, 0);
}

// 8 f32 -> bf16x8 via compiler bf16 casts (hw cvt on gfx950, RNE)
__device__ __forceinline__ bf16x8 cvt8(f32x4 a, f32x4 b) {
  bf16x8 r;
#pragma unroll
  for (int i = 0; i < 4; ++i) {
    union { __hip_bfloat16 h; short s; } u;
    u.h = __hip_bfloat16(a[i]);
    r[i] = u.s;
  }
#pragma unroll
  for (int i = 0; i < 4; ++i) {
    union { __hip_bfloat16 h; short s; } u;
    u.h = __hip_bfloat16(b[i]);
    r[4 + i] = u.s;
  }
  return r;
}

// ---------- prep kernels ----------
__global__ __launch_bounds__(256) void transpose_cvt_k(const float* __restrict__ W,
    unsigned short* __restrict__ Wt, int K, int N, float scale) {
  int i = blockIdx.x * 256 + threadIdx.x;
  if (i >= N * K) return;
  int n = i / K, k = i - n * K;
  Wt[i] = f2bf(W[(long)k * N + n] * scale);
}

__global__ __launch_bounds__(256) void scale_bias_k(const float* __restrict__ b,
    float* __restrict__ bs, float scale, int n) {
  int i = blockIdx.x * 256 + threadIdx.x;
  if (i < n) bs[i] = b[i] * scale;
}

// rpbp[h][q][lc*4+kt] = rpb[h][q][kt*16+lc]  (fragment-permuted, 256 KB f32)
__global__ __launch_bounds__(256) void build_rpbp_k(const float* __restrict__ bt,
    float* __restrict__ rpbp) {
  int i = blockIdx.x * 256 + threadIdx.x;
  if (i >= 16 * 64 * 64) return;
  int kt = i & 3, lcv = (i >> 2) & 15, q = (i >> 6) & 63, h = i >> 12;
  int k = kt * 16 + lcv;
  int dh = (q >> 3) - (k >> 3) + 7;
  int dw = (q & 7) - (k & 7) + 7;
  rpbp[i] = bt[(dh * 15 + dw) * 16 + h];
}

// ---------- GEMM body (m97 structure, proven; bf16 A) ----------
template <typename OT>
__device__ __forceinline__ void gemm_body(const unsigned short* __restrict__ A,
    const unsigned short* __restrict__ Bt, const float* __restrict__ bias,
    OT* __restrict__ C, int M, int N, int K)
{
  constexpr bool O_F32 = (sizeof(OT) == 4);

  __shared__ __align__(16) char smem[32768];
  unsigned short* Asm = (unsigned short*)smem;
  unsigned short* Bsm = Asm + 8192;

  const int tn = N >> 7;
  const int nbm = M >> 7;
  const int g = blockIdx.x;
  const int xcd = g & 7;
  const int s = g >> 3;
  const int bm = xcd * (nbm >> 3) + (s / tn);
  const int bn = s - (s / tn) * tn;

  const int tid = threadIdx.x;
  const int wave = tid >> 6, lane = tid & 63;
  const int wr = wave >> 1, wc = wave & 1;
  const int lg = lane >> 4, lc = lane & 15;

  const long rowBase = (long)bm * 128;
  const int colBase = bn * 128;
  const int KT = K >> 6;

  f32x4 acc[4][4];
#pragma unroll
  for (int i = 0; i < 4; ++i)
#pragma unroll
    for (int j = 0; j < 4; ++j)
      acc[i][j] = f32x4{0.f, 0.f, 0.f, 0.f};

  const int blr = lane >> 3;
  const int bsw = (lane & 7) ^ blr;

  auto issueA = [&](int kt) {
#pragma unroll
    for (int j = 0; j < 4; ++j) {
      int r = j * 32 + wave * 8 + blr;
      gl_lds16(A + (rowBase + r) * (long)K + kt * 64 + bsw * 8,
               Asm + (j * 4 + wave) * 512);
    }
  };
  auto issueB = [&](int kt) {
#pragma unroll
    for (int j = 0; j < 4; ++j) {
      int r = j * 32 + wave * 8 + blr;
      gl_lds16(Bt + (long)(colBase + r) * K + kt * 64 + bsw * 8,
               Bsm + (j * 4 + wave) * 512);
    }
  };
  auto compute = [&]() {
#pragma unroll
    for (int ks = 0; ks < 2; ++ks) {
      const int ca = (ks * 4 + lg) ^ (lc & 7);
      bf16x8 af[4], bfr[4];
#pragma unroll
      for (int mt = 0; mt < 4; ++mt)
        af[mt] = *(const bf16x8*)(Asm + (wr * 64 + mt * 16 + lc) * 64 + ca * 8);
#pragma unroll
      for (int nt = 0; nt < 4; ++nt)
        bfr[nt] = *(const bf16x8*)(Bsm + (wc * 64 + nt * 16 + lc) * 64 + ca * 8);
#pragma unroll
      for (int mt = 0; mt < 4; ++mt)
#pragma unroll
        for (int nt = 0; nt < 4; ++nt)
          acc[mt][nt] = MFMA16(af[mt], bfr[nt], acc[mt][nt]);
    }
  };

  issueA(0); issueB(0);
  __syncthreads();

  for (int kt = 0; kt < KT; ++kt) {
    const bool more = (kt + 1 < KT);
    compute();
    __syncthreads();
    if (more) {
      issueA(kt + 1); issueB(kt + 1);
      __syncthreads();
    }
  }

  float bv[4];
#pragma unroll
  for (int nt = 0; nt < 4; ++nt)
    bv[nt] = bias[colBase + wc * 64 + nt * 16 + lc];

  if constexpr (O_F32) {
    float* Sf = (float*)smem;
#pragma unroll
    for (int h = 0; h < 2; ++h) {
      if (wr == h) {
#pragma unroll
        for (int mt = 0; mt < 4; ++mt)
#pragma unroll
          for (int nt = 0; nt < 4; ++nt)
#pragma unroll
            for (int r = 0; r < 4; ++r)
              Sf[(mt * 16 + lg * 4 + r) * 128 + wc * 64 + nt * 16 + lc] =
                  acc[mt][nt][r] + bv[nt];
      }
      __syncthreads();
#pragma unroll
      for (int p = 0; p < 8; ++p) {
        int ch = p * 256 + tid, row = ch >> 5, c = ch & 31;
        *(float4*)((float*)C + (rowBase + h * 64 + row) * N + colBase + c * 4) =
            *(const float4*)(Sf + row * 128 + c * 4);
      }
      __syncthreads();
    }
  } else {
    unsigned short* Su = (unsigned short*)smem;
#pragma unroll
    for (int h = 0; h < 2; ++h) {
      if (wr == h) {
#pragma unroll
        for (int mt = 0; mt < 4; ++mt)
#pragma unroll
          for (int nt = 0; nt < 4; ++nt)
#pragma unroll
            for (int r = 0; r < 4; ++r)
              Su[(mt * 16 + lg * 4 + r) * 128 + wc * 64 + nt * 16 + lc] =
                  f2bf(acc[mt][nt][r] + bv[nt]);
      }
      __syncthreads();
#pragma unroll
      for (int p = 0; p < 4; ++p) {
        int ch = p * 256 + tid, row = ch >> 4, c = ch & 15;
        *(uint4*)((unsigned short*)C + (rowBase + h * 64 + row) * N + colBase + c * 8) =
            *(const uint4*)(Su + row * 128 + c * 8);
      }
      __syncthreads();
    }
  }
}

__global__ __launch_bounds__(256, 4) void gemm_out_k(const unsigned short* __restrict__ A,
    const unsigned short* __restrict__ Bt, const float* __restrict__ bias,
    float* __restrict__ C, int M, int N, int K) {
  gemm_body<float>(A, Bt, bias, C, M, N, K);
}

// ---------- fused fp32-A GEMM body (measured-good via gemm_qf, R10) ----------
// m97 skeleton; A streams fp32 via global_load_lds into a 32 KB XOR-swizzled
// f32 tile ([128 rows][16 chunks of 16B], chunk ^= row&15, both sides);
// conversion to bf16 at ds_read time (hw cvt). LDS 48 KB, 3 blocks/CU.
__device__ __forceinline__ void gemm_f32a_body(const float* __restrict__ A,
    const unsigned short* __restrict__ Bt, const float* __restrict__ bias,
    unsigned short* __restrict__ C, int M, int N, int K)
{
  __shared__ __align__(16) char smem[49152];
  float* Af = (float*)smem;                               // [128][64] f32, 32 KB
  unsigned short* Bsm = (unsigned short*)(smem + 32768);  // [128][64] bf16, 16 KB

  const int tn = N >> 7;
  const int nbm = M >> 7;
  const int g = blockIdx.x;
  const int xcd = g & 7;
  const int s = g >> 3;
  const int bm = xcd * (nbm >> 3) + (s / tn);
  const int bn = s - (s / tn) * tn;

  const int tid = threadIdx.x;
  const int wave = tid >> 6, lane = tid & 63;
  const int wr = wave >> 1, wc = wave & 1;
  const int lg = lane >> 4, lc = lane & 15;

  const long rowBase = (long)bm * 128;
  const int colBase = bn * 128;
  const int KT = K >> 6;

  f32x4 acc[4][4];
#pragma unroll
  for (int i = 0; i < 4; ++i)
#pragma unroll
    for (int j = 0; j < 4; ++j)
      acc[i][j] = f32x4{0.f, 0.f, 0.f, 0.f};

  // B staging (8 chunks/row, chunk ^= row&7)
  const int blr = lane >> 3;
  const int bsw = (lane & 7) ^ blr;
  // A staging (f32, 16 chunks/row, chunk ^= row&15): issue = 4 rows x 16 chunks
  const int alr = lane >> 4;          // row-in-4
  const int achk = lane & 15;

  auto issueA = [&](int kt) {
#pragma unroll
    for (int j = 0; j < 8; ++j) {
      int r = (j * 4 + wave) * 4 + alr;
      int swc = achk ^ (r & 15);
      gl_lds16(A + (rowBase + r) * (long)K + kt * 64 + swc * 4,
               Af + (j * 4 + wave) * 256);
    }
  };
  auto issueB = [&](int kt) {
#pragma unroll
    for (int j = 0; j < 4; ++j) {
      int r = j * 32 + wave * 8 + blr;
      gl_lds16(Bt + (long)(colBase + r) * K + kt * 64 + bsw * 8,
               Bsm + (j * 4 + wave) * 512);
    }
  };
  auto compute = [&]() {
#pragma unroll
    for (int ks = 0; ks < 2; ++ks) {
      const int cb = (ks * 4 + lg) ^ (lc & 7);
      bf16x8 af[4], bfr[4];
#pragma unroll
      for (int mt = 0; mt < 4; ++mt) {
        const int row = wr * 64 + mt * 16 + lc;     // row & 15 == lc
        const int c0 = ks * 8 + lg * 2;
        f32x4 f0 = *(const f32x4*)(Af + row * 64 + ((c0)     ^ lc) * 4);
        f32x4 f1 = *(const f32x4*)(Af + row * 64 + ((c0 + 1) ^ lc) * 4);
        af[mt] = cvt8(f0, f1);
      }
#pragma unroll
      for (int nt = 0; nt < 4; ++nt)
        bfr[nt] = *(const bf16x8*)(Bsm + (wc * 64 + nt * 16 + lc) * 64 + cb * 8);
#pragma unroll
      for (int mt = 0; mt < 4; ++mt)
#pragma unroll
        for (int nt = 0; nt < 4; ++nt)
          acc[mt][nt] = MFMA16(af[mt], bfr[nt], acc[mt][nt]);
    }
  };

  issueA(0); issueB(0);
  __syncthreads();

  for (int kt = 0; kt < KT; ++kt) {
    const bool more = (kt + 1 < KT);
    compute();
    __syncthreads();
    if (more) {
      issueA(kt + 1); issueB(kt + 1);
      __syncthreads();
    }
  }

  float bv[4];
#pragma unroll
  for (int nt = 0; nt < 4; ++nt)
    bv[nt] = bias[colBase + wc * 64 + nt * 16 + lc];

  // bf16 epilogue (staged, full-sector stores)
  unsigned short* Su = (unsigned short*)smem;
#pragma unroll
  for (int h = 0; h < 2; ++h) {
    __syncthreads();
    if (wr == h) {
#pragma unroll
      for (int mt = 0; mt < 4; ++mt)
#pragma unroll
        for (int nt = 0; nt < 4; ++nt)
#pragma unroll
          for (int r = 0; r < 4; ++r)
            Su[(mt * 16 + lg * 4 + r) * 128 + wc * 64 + nt * 16 + lc] =
                f2bf(acc[mt][nt][r] + bv[nt]);
    }
    __syncthreads();
#pragma unroll
    for (int p = 0; p < 4; ++p) {
      int ch = p * 256 + tid, row = ch >> 4, c = ch & 15;
      *(uint4*)(C + (rowBase + h * 64 + row) * N + colBase + c * 8) =
          *(const uint4*)(Su + row * 128 + c * 8);
    }
  }
}

__global__ __launch_bounds__(256, 3) void gemm_qf_k(const float* __restrict__ A,
    const unsigned short* __restrict__ Bt, const float* __restrict__ bias,
    unsigned short* __restrict__ C, int M, int N, int K) {
  gemm_f32a_body(A, Bt, bias, C, M, N, K);
}
__global__ __launch_bounds__(256, 3) void gemm_kvf_k(const float* __restrict__ A,
    const unsigned short* __restrict__ Bt, const float* __restrict__ bias,
    unsigned short* __restrict__ C, int M, int N, int K) {
  gemm_f32a_body(A, Bt, bias, C, M, N, K);
}

// ---------- fused window attention, head-cooperative (R8, measured) ----------
__global__ __launch_bounds__(256, 5) void attn_k(
    const unsigned short* __restrict__ qh,   // [B*64][512] bf16
    const unsigned short* __restrict__ kvh,  // [B*64][1024] bf16 (k | v)
    const float* __restrict__ mask,          // [64][64][64] f32
    const float* __restrict__ rpbp,          // [16][64][64] f32 permuted
    unsigned short* __restrict__ x)          // [B*64][512] bf16
{
  __shared__ unsigned short P[64][68];       // 8704 B (wave w: rows w*16..)
  __shared__ unsigned short Vt[2][32][68];   // 8704 B, double-buffered V^T
  __shared__ unsigned short maskS[64][68];   // 8704 B, permuted bf16 mask
  __shared__ unsigned short xs[4][16][40];   // 5120 B, out-staging

  const int b = blockIdx.x;
  const int w = b & 63;
  const int tid = threadIdx.x;
  const int wave = tid >> 6, lane = tid & 63;
  const int lg = lane >> 4, lc = lane & 15;
  const long rowQ = (long)b * 64;

  // stage mask once (permuted: col = (k&15)*4 + (k>>4))
#pragma unroll
  for (int t = 0; t < 16; ++t) {
    int i = t * 256 + tid;
    int qq = i >> 6, k = i & 63;
    maskS[qq][(k & 15) * 4 + (k >> 4)] = f2bf(mask[w * 4096 + i]);
  }

  // V staging geometry: thread -> (token = tid>>2, d-group = tid&3)
  const int vtok = tid >> 2, vg = tid & 3;
  const unsigned short* vbase = kvh + (rowQ + vtok) * 1024 + 512 + vg * 8;

  // stage V[head 0] into buf 0
  {
    u16x8 v0 = *(const u16x8*)(vbase);
#pragma unroll
    for (int j = 0; j < 8; ++j) Vt[0][vg * 8 + j][vtok] = v0[j];
  }
  __syncthreads();

  for (int h = 0; h < 16; ++h) {
    const int cur = h & 1;

    // prefetch next head's V slice into regs (hidden under QK+softmax)
    u16x8 vn;
    if (h < 15) vn = *(const u16x8*)(vbase + (h + 1) * 32);

    // Q frag (wave's 16 rows) + K frags (all 64 tokens, L1-shared)
    bf16x8 qf = *(const bf16x8*)(qh + (rowQ + wave * 16 + lc) * 512 + h * 32 + lg * 8);
    bf16x8 kf[4];
#pragma unroll
    for (int kt = 0; kt < 4; ++kt)
      kf[kt] = *(const bf16x8*)(kvh + (rowQ + kt * 16 + lc) * 1024 + h * 32 + lg * 8);

    f32x4 acc[4];
#pragma unroll
    for (int kt = 0; kt < 4; ++kt) acc[kt] = f32x4{0.f, 0.f, 0.f, 0.f};
#pragma unroll
    for (int kt = 0; kt < 4; ++kt) acc[kt] = MFMA16(qf, kf[kt], acc[kt]);

    // softmax: lane handles rows q = wave*16 + lg*4 + r
    float pden[4];
#pragma unroll
    for (int r = 0; r < 4; ++r) {
      const int qrow = wave * 16 + lg * 4 + r;
      f32x4 rp = *(const f32x4*)(rpbp + (h << 12) + qrow * 64 + lc * 4);
      ushort4 mv = *(const ushort4*)&maskS[qrow][lc * 4];
      float sc[4];
      sc[0] = acc[0][r] + rp[0] + bf2f(mv.x);
      sc[1] = acc[1][r] + rp[1] + bf2f(mv.y);
      sc[2] = acc[2][r] + rp[2] + bf2f(mv.z);
      sc[3] = acc[3][r] + rp[3] + bf2f(mv.w);
      float mx = fmaxf(fmaxf(sc[0], sc[1]), fmaxf(sc[2], sc[3]));
      mx = fmaxf(mx, __shfl_xor(mx, 1));
      mx = fmaxf(mx, __shfl_xor(mx, 2));
      mx = fmaxf(mx, __shfl_xor(mx, 4));
      mx = fmaxf(mx, __shfl_xor(mx, 8));
      float s = 0.f;
#pragma unroll
      for (int kt = 0; kt < 4; ++kt) { sc[kt] = __expf(sc[kt] - mx); s += sc[kt]; }
      s += __shfl_xor(s, 1);
      s += __shfl_xor(s, 2);
      s += __shfl_xor(s, 4);
      s += __shfl_xor(s, 8);
      pden[r] = 1.f / s;
#pragma unroll
      for (int kt = 0; kt < 4; ++kt)
        P[qrow][kt * 16 + lc] = f2bf(sc[kt]);
    }

    // write next head's V^T into the other buffer (readers finished last iter)
    if (h < 15) {
#pragma unroll
      for (int j = 0; j < 8; ++j) Vt[cur ^ 1][vg * 8 + j][vtok] = vn[j];
    }

    // PV: out[q][d] for wave's rows; P rows are wave-private (no barrier)
    f32x4 xacc[2];
    xacc[0] = f32x4{0.f, 0.f, 0.f, 0.f};
    xacc[1] = f32x4{0.f, 0.f, 0.f, 0.f};
#pragma unroll
    for (int ks = 0; ks < 2; ++ks) {
      bf16x8 pa = *(const bf16x8*)&P[wave * 16 + lc][ks * 32 + lg * 8];
      bf16x8 vb0 = *(const bf16x8*)&Vt[cur][lc][ks * 32 + lg * 8];
      bf16x8 vb1 = *(const bf16x8*)&Vt[cur][16 + lc][ks * 32 + lg * 8];
      xacc[0] = MFMA16(pa, vb0, xacc[0]);
      xacc[1] = MFMA16(pa, vb1, xacc[1]);
    }

    // normalize -> xs -> full-sector 64B stores
#pragma unroll
    for (int dt = 0; dt < 2; ++dt)
#pragma unroll
      for (int r = 0; r < 4; ++r)
        xs[wave][lg * 4 + r][dt * 16 + lc] = f2bf(xacc[dt][r] * pden[r]);
    {
      int row = lane >> 2, c = lane & 3;
      uint4 v = *(const uint4*)&xs[wave][row][c * 8];
      *(uint4*)(x + (rowQ + wave * 16 + row) * 512 + h * 32 + c * 8) = v;
    }

    __syncthreads();  // Vt[cur] readers done before iter h+1 writes it
  }
}

extern "C" void kernel_launch(void* const* d_in, const int* in_sizes, int n_in,
                              void* d_out, int out_size, void* d_ws, size_t ws_size,
                              hipStream_t stream) {
  const float* q    = (const float*)d_in[0];
  const float* kv   = (const float*)d_in[1];
  const float* mask = (const float*)d_in[2];
  const float* Wq   = (const float*)d_in[3];
  const float* bq   = (const float*)d_in[4];
  const float* Wkv  = (const float*)d_in[5];
  const float* bkv  = (const float*)d_in[6];
  const float* btab = (const float*)d_in[7];
  const float* Wp   = (const float*)d_in[8];
  const float* bp   = (const float*)d_in[9];
  float* out = (float*)d_out;

  const int M = 4096 * 64;  // 262144 rows

  char* ws = (char*)d_ws;
  const size_t OFF_QH   = 0;                               // 256 MB
  const size_t OFF_KVH  = OFF_QH + (size_t)M * 512 * 2;    // 512 MB
  const size_t OFF_SCR  = OFF_KVH + (size_t)M * 1024 * 2;  // 256 MB (xb)
  const size_t OFF_WQT  = OFF_SCR + (size_t)M * 512 * 2;
  const size_t OFF_WKVT = OFF_WQT + 512 * 512 * 2;
  const size_t OFF_WPT  = OFF_WKVT + 1024 * 512 * 2;
  const size_t OFF_RPBP = OFF_WPT + 512 * 512 * 2;         // 256 KB
  const size_t OFF_BQS  = OFF_RPBP + 16 * 64 * 64 * 4;     // 2 KB

  unsigned short* qh    = (unsigned short*)(ws + OFF_QH);
  unsigned short* kvh   = (unsigned short*)(ws + OFF_KVH);
  unsigned short* scr   = (unsigned short*)(ws + OFF_SCR); // xb
  unsigned short* Wq_t  = (unsigned short*)(ws + OFF_WQT);
  unsigned short* Wkv_t = (unsigned short*)(ws + OFF_WKVT);
  unsigned short* Wp_t  = (unsigned short*)(ws + OFF_WPT);
  float* rpbp           = (float*)(ws + OFF_RPBP);
  float* bq_s           = (float*)(ws + OFF_BQS);

  transpose_cvt_k<<<(512 * 512 + 255) / 256, 256, 0, stream>>>(Wq, Wq_t, 512, 512, SCALEF);
  transpose_cvt_k<<<(512 * 1024 + 255) / 256, 256, 0, stream>>>(Wkv, Wkv_t, 512, 1024, 1.0f);
  transpose_cvt_k<<<(512 * 512 + 255) / 256, 256, 0, stream>>>(Wp, Wp_t, 512, 512, 1.0f);
  scale_bias_k<<<2, 256, 0, stream>>>(bq, bq_s, SCALEF, 512);
  build_rpbp_k<<<(16 * 64 * 64) / 256, 256, 0, stream>>>(btab, rpbp);

  // KV-proj reads fp32 kv directly (fused conversion; cvt pass eliminated)
  gemm_kvf_k<<<(M / 128) * (1024 / 128), 256, 0, stream>>>(kv, Wkv_t, bkv, kvh, M, 1024, 512);

  // Q-proj reads fp32 q directly (fused conversion)
  gemm_qf_k<<<(M / 128) * (512 / 128), 256, 0, stream>>>(q, Wq_t, bq_s, qh, M, 512, 512);

  // attention (scratch holds xb)
  attn_k<<<4096, 256, 0, stream>>>(qh, kvh, mask, rpbp, scr);

  gemm_out_k<<<(M / 128) * (512 / 128), 256, 0, stream>>>(scr, Wp_t, bp, out, M, 512, 512);

  (void)in_sizes; (void)n_in; (void)out_size; (void)ws_size;
}

// Round 12
// 1280.212 us; speedup vs baseline: 2.9967x; 1.0142x over previous
//
#include <hip/hip_runtime.h>
#include <hip/hip_bf16.h>

typedef short bf16x8 __attribute__((ext_vector_type(8)));
typedef unsigned short u16x8 __attribute__((ext_vector_type(8)));
typedef float f32x4 __attribute__((ext_vector_type(4)));

#define MFMA16(a, b, c) __builtin_amdgcn_mfma_f32_16x16x32_bf16((a), (b), (c), 0, 0, 0)

#define SCALEF 0.17677669529663687f  // 32^-0.5

__device__ __forceinline__ unsigned short f2bf(float f) {
  union { float f; unsigned u; } v; v.f = f;
  unsigned r = v.u + 0x7fffu + ((v.u >> 16) & 1u);  // RNE
  return (unsigned short)(r >> 16);
}
__device__ __forceinline__ float bf2f(unsigned short b) {
  union { unsigned u; float f; } v; v.u = ((unsigned)b) << 16;
  return v.f;
}

__device__ __forceinline__ void gl_lds16(const void* g, void* l) {
  __builtin_amdgcn_global_load_lds(
      (const __attribute__((address_space(1))) void*)g,
      (__attribute__((address_space(3))) void*)l, 16, 0, 0);
}

// 8 f32 -> bf16x8 via compiler bf16 casts (hw cvt on gfx950, RNE)
__device__ __forceinline__ bf16x8 cvt8(f32x4 a, f32x4 b) {
  bf16x8 r;
#pragma unroll
  for (int i = 0; i < 4; ++i) {
    union { __hip_bfloat16 h; short s; } u;
    u.h = __hip_bfloat16(a[i]);
    r[i] = u.s;
  }
#pragma unroll
  for (int i = 0; i < 4; ++i) {
    union { __hip_bfloat16 h; short s; } u;
    u.h = __hip_bfloat16(b[i]);
    r[4 + i] = u.s;
  }
  return r;
}

// ---------- merged prep kernel (weights transpose+cvt, bias scale, rpb) ----
// ranges: [0,256K) WqT*SCALE | [256K,768K) WkvT | [768K,1M) WpT |
//         [1M,1M+512) bq*SCALE | then rpbp (16*64*64)
__global__ __launch_bounds__(256) void prep_k(
    const float* __restrict__ Wq, const float* __restrict__ Wkv,
    const float* __restrict__ Wp, const float* __restrict__ bq,
    const float* __restrict__ bt,
    unsigned short* __restrict__ WqT, unsigned short* __restrict__ WkvT,
    unsigned short* __restrict__ WpT, float* __restrict__ bqs,
    float* __restrict__ rpbp)
{
  int i = blockIdx.x * 256 + threadIdx.x;
  if (i < 262144) {                       // WqT[n][k] = Wq[k][n]*scale
    int n = i >> 9, k = i & 511;
    WqT[i] = f2bf(Wq[k * 512 + n] * SCALEF);
  } else if (i < 786432) {                // WkvT (N=1024)
    int j = i - 262144;
    int n = j >> 9, k = j & 511;
    WkvT[j] = f2bf(Wkv[k * 1024 + n]);
  } else if (i < 1048576) {               // WpT
    int j = i - 786432;
    int n = j >> 9, k = j & 511;
    WpT[j] = f2bf(Wp[k * 512 + n]);
  } else if (i < 1049088) {               // bq scaled
    int j = i - 1048576;
    bqs[j] = bq[j] * SCALEF;
  } else if (i < 1114624) {               // rpbp[h][q][lc*4+kt]
    int j = i - 1049088;
    int kt = j & 3, lcv = (j >> 2) & 15, qq = (j >> 6) & 63, h = j >> 12;
    int k = kt * 16 + lcv;
    int dh = (qq >> 3) - (k >> 3) + 7;
    int dw = (qq & 7) - (k & 7) + 7;
    rpbp[j] = bt[(dh * 15 + dw) * 16 + h];
  }
}

// ---------- GEMM body (m97 structure, proven; bf16 A) ----------
template <typename OT>
__device__ __forceinline__ void gemm_body(const unsigned short* __restrict__ A,
    const unsigned short* __restrict__ Bt, const float* __restrict__ bias,
    OT* __restrict__ C, int M, int N, int K)
{
  constexpr bool O_F32 = (sizeof(OT) == 4);

  __shared__ __align__(16) char smem[32768];
  unsigned short* Asm = (unsigned short*)smem;
  unsigned short* Bsm = Asm + 8192;

  const int tn = N >> 7;
  const int nbm = M >> 7;
  const int g = blockIdx.x;
  const int xcd = g & 7;
  const int s = g >> 3;
  const int bm = xcd * (nbm >> 3) + (s / tn);
  const int bn = s - (s / tn) * tn;

  const int tid = threadIdx.x;
  const int wave = tid >> 6, lane = tid & 63;
  const int wr = wave >> 1, wc = wave & 1;
  const int lg = lane >> 4, lc = lane & 15;

  const long rowBase = (long)bm * 128;
  const int colBase = bn * 128;
  const int KT = K >> 6;

  f32x4 acc[4][4];
#pragma unroll
  for (int i = 0; i < 4; ++i)
#pragma unroll
    for (int j = 0; j < 4; ++j)
      acc[i][j] = f32x4{0.f, 0.f, 0.f, 0.f};

  const int blr = lane >> 3;
  const int bsw = (lane & 7) ^ blr;

  auto issueA = [&](int kt) {
#pragma unroll
    for (int j = 0; j < 4; ++j) {
      int r = j * 32 + wave * 8 + blr;
      gl_lds16(A + (rowBase + r) * (long)K + kt * 64 + bsw * 8,
               Asm + (j * 4 + wave) * 512);
    }
  };
  auto issueB = [&](int kt) {
#pragma unroll
    for (int j = 0; j < 4; ++j) {
      int r = j * 32 + wave * 8 + blr;
      gl_lds16(Bt + (long)(colBase + r) * K + kt * 64 + bsw * 8,
               Bsm + (j * 4 + wave) * 512);
    }
  };
  auto compute = [&]() {
#pragma unroll
    for (int ks = 0; ks < 2; ++ks) {
      const int ca = (ks * 4 + lg) ^ (lc & 7);
      bf16x8 af[4], bfr[4];
#pragma unroll
      for (int mt = 0; mt < 4; ++mt)
        af[mt] = *(const bf16x8*)(Asm + (wr * 64 + mt * 16 + lc) * 64 + ca * 8);
#pragma unroll
      for (int nt = 0; nt < 4; ++nt)
        bfr[nt] = *(const bf16x8*)(Bsm + (wc * 64 + nt * 16 + lc) * 64 + ca * 8);
#pragma unroll
      for (int mt = 0; mt < 4; ++mt)
#pragma unroll
        for (int nt = 0; nt < 4; ++nt)
          acc[mt][nt] = MFMA16(af[mt], bfr[nt], acc[mt][nt]);
    }
  };

  issueA(0); issueB(0);
  __syncthreads();

  for (int kt = 0; kt < KT; ++kt) {
    const bool more = (kt + 1 < KT);
    compute();
    __syncthreads();
    if (more) {
      issueA(kt + 1); issueB(kt + 1);
      __syncthreads();
    }
  }

  float bv[4];
#pragma unroll
  for (int nt = 0; nt < 4; ++nt)
    bv[nt] = bias[colBase + wc * 64 + nt * 16 + lc];

  if constexpr (O_F32) {
    float* Sf = (float*)smem;
#pragma unroll
    for (int h = 0; h < 2; ++h) {
      if (wr == h) {
#pragma unroll
        for (int mt = 0; mt < 4; ++mt)
#pragma unroll
          for (int nt = 0; nt < 4; ++nt)
#pragma unroll
            for (int r = 0; r < 4; ++r)
              Sf[(mt * 16 + lg * 4 + r) * 128 + wc * 64 + nt * 16 + lc] =
                  acc[mt][nt][r] + bv[nt];
      }
      __syncthreads();
#pragma unroll
      for (int p = 0; p < 8; ++p) {
        int ch = p * 256 + tid, row = ch >> 5, c = ch & 31;
        *(float4*)((float*)C + (rowBase + h * 64 + row) * N + colBase + c * 4) =
            *(const float4*)(Sf + row * 128 + c * 4);
      }
      __syncthreads();
    }
  } else {
    unsigned short* Su = (unsigned short*)smem;
#pragma unroll
    for (int h = 0; h < 2; ++h) {
      if (wr == h) {
#pragma unroll
        for (int mt = 0; mt < 4; ++mt)
#pragma unroll
          for (int nt = 0; nt < 4; ++nt)
#pragma unroll
            for (int r = 0; r < 4; ++r)
              Su[(mt * 16 + lg * 4 + r) * 128 + wc * 64 + nt * 16 + lc] =
                  f2bf(acc[mt][nt][r] + bv[nt]);
      }
      __syncthreads();
#pragma unroll
      for (int p = 0; p < 4; ++p) {
        int ch = p * 256 + tid, row = ch >> 4, c = ch & 15;
        *(uint4*)((unsigned short*)C + (rowBase + h * 64 + row) * N + colBase + c * 8) =
            *(const uint4*)(Su + row * 128 + c * 8);
      }
      __syncthreads();
    }
  }
}

__global__ __launch_bounds__(256, 4) void gemm_out_k(const unsigned short* __restrict__ A,
    const unsigned short* __restrict__ Bt, const float* __restrict__ bias,
    float* __restrict__ C, int M, int N, int K) {
  gemm_body<float>(A, Bt, bias, C, M, N, K);
}

// ---------- fused fp32-A GEMM body (measured-good, R10/R11) ----------
// m97 skeleton; A streams fp32 via global_load_lds into a 32 KB XOR-swizzled
// f32 tile; conversion to bf16 at ds_read time. smem passed in (49152 B) so
// the twice-inlined body in the merged kernel shares ONE allocation.
__device__ __forceinline__ void gemm_f32a_body(char* smem, int g,
    const float* __restrict__ A, const unsigned short* __restrict__ Bt,
    const float* __restrict__ bias, unsigned short* __restrict__ C,
    int M, int N, int K)
{
  float* Af = (float*)smem;                               // [128][64] f32, 32 KB
  unsigned short* Bsm = (unsigned short*)(smem + 32768);  // [128][64] bf16, 16 KB

  const int tn = N >> 7;
  const int nbm = M >> 7;
  const int xcd = g & 7;
  const int s = g >> 3;
  const int bm = xcd * (nbm >> 3) + (s / tn);
  const int bn = s - (s / tn) * tn;

  const int tid = threadIdx.x;
  const int wave = tid >> 6, lane = tid & 63;
  const int wr = wave >> 1, wc = wave & 1;
  const int lg = lane >> 4, lc = lane & 15;

  const long rowBase = (long)bm * 128;
  const int colBase = bn * 128;
  const int KT = K >> 6;

  f32x4 acc[4][4];
#pragma unroll
  for (int i = 0; i < 4; ++i)
#pragma unroll
    for (int j = 0; j < 4; ++j)
      acc[i][j] = f32x4{0.f, 0.f, 0.f, 0.f};

  // B staging (8 chunks/row, chunk ^= row&7)
  const int blr = lane >> 3;
  const int bsw = (lane & 7) ^ blr;
  // A staging (f32, 16 chunks/row, chunk ^= row&15)
  const int alr = lane >> 4;
  const int achk = lane & 15;

  auto issueA = [&](int kt) {
#pragma unroll
    for (int j = 0; j < 8; ++j) {
      int r = (j * 4 + wave) * 4 + alr;
      int swc = achk ^ (r & 15);
      gl_lds16(A + (rowBase + r) * (long)K + kt * 64 + swc * 4,
               Af + (j * 4 + wave) * 256);
    }
  };
  auto issueB = [&](int kt) {
#pragma unroll
    for (int j = 0; j < 4; ++j) {
      int r = j * 32 + wave * 8 + blr;
      gl_lds16(Bt + (long)(colBase + r) * K + kt * 64 + bsw * 8,
               Bsm + (j * 4 + wave) * 512);
    }
  };
  auto compute = [&]() {
#pragma unroll
    for (int ks = 0; ks < 2; ++ks) {
      const int cb = (ks * 4 + lg) ^ (lc & 7);
      bf16x8 af[4], bfr[4];
#pragma unroll
      for (int mt = 0; mt < 4; ++mt) {
        const int row = wr * 64 + mt * 16 + lc;     // row & 15 == lc
        const int c0 = ks * 8 + lg * 2;
        f32x4 f0 = *(const f32x4*)(Af + row * 64 + ((c0)     ^ lc) * 4);
        f32x4 f1 = *(const f32x4*)(Af + row * 64 + ((c0 + 1) ^ lc) * 4);
        af[mt] = cvt8(f0, f1);
      }
#pragma unroll
      for (int nt = 0; nt < 4; ++nt)
        bfr[nt] = *(const bf16x8*)(Bsm + (wc * 64 + nt * 16 + lc) * 64 + cb * 8);
#pragma unroll
      for (int mt = 0; mt < 4; ++mt)
#pragma unroll
        for (int nt = 0; nt < 4; ++nt)
          acc[mt][nt] = MFMA16(af[mt], bfr[nt], acc[mt][nt]);
    }
  };

  issueA(0); issueB(0);
  __syncthreads();

  for (int kt = 0; kt < KT; ++kt) {
    const bool more = (kt + 1 < KT);
    compute();
    __syncthreads();
    if (more) {
      issueA(kt + 1); issueB(kt + 1);
      __syncthreads();
    }
  }

  float bv[4];
#pragma unroll
  for (int nt = 0; nt < 4; ++nt)
    bv[nt] = bias[colBase + wc * 64 + nt * 16 + lc];

  // bf16 epilogue (staged, full-sector stores)
  unsigned short* Su = (unsigned short*)smem;
#pragma unroll
  for (int h = 0; h < 2; ++h) {
    __syncthreads();
    if (wr == h) {
#pragma unroll
      for (int mt = 0; mt < 4; ++mt)
#pragma unroll
        for (int nt = 0; nt < 4; ++nt)
#pragma unroll
          for (int r = 0; r < 4; ++r)
            Su[(mt * 16 + lg * 4 + r) * 128 + wc * 64 + nt * 16 + lc] =
                f2bf(acc[mt][nt][r] + bv[nt]);
    }
    __syncthreads();
#pragma unroll
    for (int p = 0; p < 4; ++p) {
      int ch = p * 256 + tid, row = ch >> 4, c = ch & 15;
      *(uint4*)(C + (rowBase + h * 64 + row) * N + colBase + c * 8) =
          *(const uint4*)(Su + row * 128 + c * 8);
    }
  }
}

// Merged Q-proj + KV-proj: blocks [0, M/128*8) do KV, rest do Q.
// Q blocks backfill the KV tail round; one launch boundary removed.
__global__ __launch_bounds__(256, 3) void gemm_qkv_k(
    const float* __restrict__ kv, const float* __restrict__ q,
    const unsigned short* __restrict__ WkvT, const unsigned short* __restrict__ WqT,
    const float* __restrict__ bkv, const float* __restrict__ bqs,
    unsigned short* __restrict__ kvh, unsigned short* __restrict__ qh, int M)
{
  __shared__ __align__(16) char smem[49152];
  const int nbkv = (M >> 7) * 8;
  if ((int)blockIdx.x < nbkv)
    gemm_f32a_body(smem, blockIdx.x, kv, WkvT, bkv, kvh, M, 1024, 512);
  else
    gemm_f32a_body(smem, blockIdx.x - nbkv, q, WqT, bqs, qh, M, 512, 512);
}

// ---------- fused window attention, head-cooperative (R8, measured) ----------
__global__ __launch_bounds__(256, 5) void attn_k(
    const unsigned short* __restrict__ qh,   // [B*64][512] bf16
    const unsigned short* __restrict__ kvh,  // [B*64][1024] bf16 (k | v)
    const float* __restrict__ mask,          // [64][64][64] f32
    const float* __restrict__ rpbp,          // [16][64][64] f32 permuted
    unsigned short* __restrict__ x)          // [B*64][512] bf16
{
  __shared__ unsigned short P[64][68];       // 8704 B (wave w: rows w*16..)
  __shared__ unsigned short Vt[2][32][68];   // 8704 B, double-buffered V^T
  __shared__ unsigned short maskS[64][68];   // 8704 B, permuted bf16 mask
  __shared__ unsigned short xs[4][16][40];   // 5120 B, out-staging

  const int b = blockIdx.x;
  const int w = b & 63;
  const int tid = threadIdx.x;
  const int wave = tid >> 6, lane = tid & 63;
  const int lg = lane >> 4, lc = lane & 15;
  const long rowQ = (long)b * 64;

  // stage mask once (permuted: col = (k&15)*4 + (k>>4))
#pragma unroll
  for (int t = 0; t < 16; ++t) {
    int i = t * 256 + tid;
    int qq = i >> 6, k = i & 63;
    maskS[qq][(k & 15) * 4 + (k >> 4)] = f2bf(mask[w * 4096 + i]);
  }

  // V staging geometry: thread -> (token = tid>>2, d-group = tid&3)
  const int vtok = tid >> 2, vg = tid & 3;
  const unsigned short* vbase = kvh + (rowQ + vtok) * 1024 + 512 + vg * 8;

  // stage V[head 0] into buf 0
  {
    u16x8 v0 = *(const u16x8*)(vbase);
#pragma unroll
    for (int j = 0; j < 8; ++j) Vt[0][vg * 8 + j][vtok] = v0[j];
  }
  __syncthreads();

  for (int h = 0; h < 16; ++h) {
    const int cur = h & 1;

    // prefetch next head's V slice into regs (hidden under QK+softmax)
    u16x8 vn;
    if (h < 15) vn = *(const u16x8*)(vbase + (h + 1) * 32);

    // Q frag (wave's 16 rows) + K frags (all 64 tokens, L1-shared)
    bf16x8 qf = *(const bf16x8*)(qh + (rowQ + wave * 16 + lc) * 512 + h * 32 + lg * 8);
    bf16x8 kf[4];
#pragma unroll
    for (int kt = 0; kt < 4; ++kt)
      kf[kt] = *(const bf16x8*)(kvh + (rowQ + kt * 16 + lc) * 1024 + h * 32 + lg * 8);

    f32x4 acc[4];
#pragma unroll
    for (int kt = 0; kt < 4; ++kt) acc[kt] = f32x4{0.f, 0.f, 0.f, 0.f};
#pragma unroll
    for (int kt = 0; kt < 4; ++kt) acc[kt] = MFMA16(qf, kf[kt], acc[kt]);

    // softmax: lane handles rows q = wave*16 + lg*4 + r
    float pden[4];
#pragma unroll
    for (int r = 0; r < 4; ++r) {
      const int qrow = wave * 16 + lg * 4 + r;
      f32x4 rp = *(const f32x4*)(rpbp + (h << 12) + qrow * 64 + lc * 4);
      ushort4 mv = *(const ushort4*)&maskS[qrow][lc * 4];
      float sc[4];
      sc[0] = acc[0][r] + rp[0] + bf2f(mv.x);
      sc[1] = acc[1][r] + rp[1] + bf2f(mv.y);
      sc[2] = acc[2][r] + rp[2] + bf2f(mv.z);
      sc[3] = acc[3][r] + rp[3] + bf2f(mv.w);
      float mx = fmaxf(fmaxf(sc[0], sc[1]), fmaxf(sc[2], sc[3]));
      mx = fmaxf(mx, __shfl_xor(mx, 1));
      mx = fmaxf(mx, __shfl_xor(mx, 2));
      mx = fmaxf(mx, __shfl_xor(mx, 4));
      mx = fmaxf(mx, __shfl_xor(mx, 8));
      float s = 0.f;
#pragma unroll
      for (int kt = 0; kt < 4; ++kt) { sc[kt] = __expf(sc[kt] - mx); s += sc[kt]; }
      s += __shfl_xor(s, 1);
      s += __shfl_xor(s, 2);
      s += __shfl_xor(s, 4);
      s += __shfl_xor(s, 8);
      pden[r] = 1.f / s;
#pragma unroll
      for (int kt = 0; kt < 4; ++kt)
        P[qrow][kt * 16 + lc] = f2bf(sc[kt]);
    }

    // write next head's V^T into the other buffer (readers finished last iter)
    if (h < 15) {
#pragma unroll
      for (int j = 0; j < 8; ++j) Vt[cur ^ 1][vg * 8 + j][vtok] = vn[j];
    }

    // PV: out[q][d] for wave's rows; P rows are wave-private (no barrier)
    f32x4 xacc[2];
    xacc[0] = f32x4{0.f, 0.f, 0.f, 0.f};
    xacc[1] = f32x4{0.f, 0.f, 0.f, 0.f};
#pragma unroll
    for (int ks = 0; ks < 2; ++ks) {
      bf16x8 pa = *(const bf16x8*)&P[wave * 16 + lc][ks * 32 + lg * 8];
      bf16x8 vb0 = *(const bf16x8*)&Vt[cur][lc][ks * 32 + lg * 8];
      bf16x8 vb1 = *(const bf16x8*)&Vt[cur][16 + lc][ks * 32 + lg * 8];
      xacc[0] = MFMA16(pa, vb0, xacc[0]);
      xacc[1] = MFMA16(pa, vb1, xacc[1]);
    }

    // normalize -> xs -> full-sector 64B stores
#pragma unroll
    for (int dt = 0; dt < 2; ++dt)
#pragma unroll
      for (int r = 0; r < 4; ++r)
        xs[wave][lg * 4 + r][dt * 16 + lc] = f2bf(xacc[dt][r] * pden[r]);
    {
      int row = lane >> 2, c = lane & 3;
      uint4 v = *(const uint4*)&xs[wave][row][c * 8];
      *(uint4*)(x + (rowQ + wave * 16 + row) * 512 + h * 32 + c * 8) = v;
    }

    __syncthreads();  // Vt[cur] readers done before iter h+1 writes it
  }
}

extern "C" void kernel_launch(void* const* d_in, const int* in_sizes, int n_in,
                              void* d_out, int out_size, void* d_ws, size_t ws_size,
                              hipStream_t stream) {
  const float* q    = (const float*)d_in[0];
  const float* kv   = (const float*)d_in[1];
  const float* mask = (const float*)d_in[2];
  const float* Wq   = (const float*)d_in[3];
  const float* bq   = (const float*)d_in[4];
  const float* Wkv  = (const float*)d_in[5];
  const float* bkv  = (const float*)d_in[6];
  const float* btab = (const float*)d_in[7];
  const float* Wp   = (const float*)d_in[8];
  const float* bp   = (const float*)d_in[9];
  float* out = (float*)d_out;

  const int M = 4096 * 64;  // 262144 rows

  char* ws = (char*)d_ws;
  const size_t OFF_QH   = 0;                               // 256 MB
  const size_t OFF_KVH  = OFF_QH + (size_t)M * 512 * 2;    // 512 MB
  const size_t OFF_SCR  = OFF_KVH + (size_t)M * 1024 * 2;  // 256 MB (xb)
  const size_t OFF_WQT  = OFF_SCR + (size_t)M * 512 * 2;
  const size_t OFF_WKVT = OFF_WQT + 512 * 512 * 2;
  const size_t OFF_WPT  = OFF_WKVT + 1024 * 512 * 2;
  const size_t OFF_RPBP = OFF_WPT + 512 * 512 * 2;         // 256 KB
  const size_t OFF_BQS  = OFF_RPBP + 16 * 64 * 64 * 4;     // 2 KB

  unsigned short* qh    = (unsigned short*)(ws + OFF_QH);
  unsigned short* kvh   = (unsigned short*)(ws + OFF_KVH);
  unsigned short* scr   = (unsigned short*)(ws + OFF_SCR); // xb
  unsigned short* Wq_t  = (unsigned short*)(ws + OFF_WQT);
  unsigned short* Wkv_t = (unsigned short*)(ws + OFF_WKVT);
  unsigned short* Wp_t  = (unsigned short*)(ws + OFF_WPT);
  float* rpbp           = (float*)(ws + OFF_RPBP);
  float* bq_s           = (float*)(ws + OFF_BQS);

  // merged prep: 1114624 elems = 4354 blocks exactly
  prep_k<<<4354, 256, 0, stream>>>(Wq, Wkv, Wp, bq, btab,
                                   Wq_t, Wkv_t, Wp_t, bq_s, rpbp);

  // merged Q+KV projection (fp32 A, fused conversion)
  const int nbkv = (M / 128) * 8;   // 16384
  const int nbq  = (M / 128) * 4;   // 8192
  gemm_qkv_k<<<nbkv + nbq, 256, 0, stream>>>(kv, q, Wkv_t, Wq_t, bkv, bq_s,
                                             kvh, qh, M);

  // attention (scratch holds xb)
  attn_k<<<4096, 256, 0, stream>>>(qh, kvh, mask, rpbp, scr);

  gemm_out_k<<<(M / 128) * (512 / 128), 256, 0, stream>>>(scr, Wp_t, bp, out, M, 512, 512);

  (void)in_sizes; (void)n_in; (void)out_size; (void)ws_size;
}